// Round 4
// baseline (355.954 us; speedup 1.0000x reference)
//
#include <hip/hip_runtime.h>
#include <math.h>

#define B 4096
#define C 5
#define NNEG 20
#define D 128
#define NROWS (C + C * NNEG)  // 105 rows per batch element (5 pos + 100 neg)

// stable log sigmoid: logsig(x) = min(x,0) - log1p(exp(-|x|))
__device__ __forceinline__ float log_sigmoid(float x) {
    return fminf(x, 0.0f) - log1pf(__expf(-fabsf(x)));
}

// One block per batch element b. 512 threads = 8 waves = 64 row-groups.
// Each 8-lane group owns row slots g and g+64 -> only 2 passes per wave
// (half the serial chain of the 256-thread version, ~1.4x the resident
// waves). Lane j of a group reads float4s at dims 4j+32k (k=0..3):
// 128B-contiguous per group per load instruction.
// All embedding offsets are 32-bit (tables < 2GB) to cut address VALU.
__global__ __launch_bounds__(512) void sgns_partial(
    const int* __restrict__ iword,
    const int* __restrict__ owords,
    const int* __restrict__ nwords,
    const float* __restrict__ emb1,
    const float* __restrict__ emb2,
    float* __restrict__ partial)
{
    const int b    = blockIdx.x;
    const int tid  = threadIdx.x;
    const int lane = tid & 63;
    const int wave = tid >> 6;       // 0..7
    const int grp  = lane >> 3;      // 0..7
    const int j    = lane & 7;       // dim-slice owner within group
    const int g    = wave * 8 + grp; // 0..63

    // v1 fragment: dims 4j+32k, k=0..3 (16 floats in registers)
    const int center = iword[b] * D;             // < 51.2M, fits int
    const float4* v1p = (const float4*)(emb1 + center);
    float4 v1f[4];
    #pragma unroll
    for (int k = 0; k < 4; ++k) v1f[k] = v1p[j + 8 * k];

    // resolve the 2 row indices (clamp invalid tail slots to row-slot 0)
    int   rOff[2];
    float sgn[2];
    bool  valid[2];
    #pragma unroll
    for (int p = 0; p < 2; ++p) {
        const int r = g + 64 * p;
        valid[p] = (r < NROWS);
        const int rr = valid[p] ? r : 0;
        const bool pos = (rr < C);
        sgn[p] = pos ? 1.0f : -1.0f;
        const int idx = pos ? owords[b * C + rr]
                            : nwords[b * (C * NNEG) + (rr - C)];
        rOff[p] = idx * D;                       // 32-bit element offset
    }

    // prefetch all 8 float4s (2 rows x 4 slices) before consuming any
    float4 rw[2][4];
    #pragma unroll
    for (int p = 0; p < 2; ++p) {
        const float4* rp = (const float4*)(emb2 + rOff[p]);
        #pragma unroll
        for (int k = 0; k < 4; ++k) rw[p][k] = rp[j + 8 * k];
    }

    float acc = 0.0f;
    #pragma unroll
    for (int p = 0; p < 2; ++p) {
        float s = 0.0f;
        #pragma unroll
        for (int k = 0; k < 4; ++k) {
            s += v1f[k].x * rw[p][k].x + v1f[k].y * rw[p][k].y
               + v1f[k].z * rw[p][k].z + v1f[k].w * rw[p][k].w;
        }
        // 3-step butterfly within the 8-lane group
        s += __shfl_xor(s, 1, 64);
        s += __shfl_xor(s, 2, 64);
        s += __shfl_xor(s, 4, 64);

        const float v = log_sigmoid(sgn[p] * s);
        acc += valid[p] ? v : 0.0f;
    }

    // acc is uniform within each 8-lane group -> reduce across groups only
    acc += __shfl_xor(acc, 8, 64);
    acc += __shfl_xor(acc, 16, 64);
    acc += __shfl_xor(acc, 32, 64);

    __shared__ float wsum[8];
    if (lane == 0) wsum[wave] = acc;
    __syncthreads();
    if (tid == 0) {
        float t = 0.0f;
        #pragma unroll
        for (int w = 0; w < 8; ++w) t += wsum[w];
        partial[b] = t;
    }
}

// Single-block final reduction: out = -(sum of all logsig terms) / (B*C)
__global__ __launch_bounds__(256) void sgns_reduce(
    const float* __restrict__ partial,
    float* __restrict__ out)
{
    const int tid = threadIdx.x;
    float acc = 0.0f;
    for (int i = tid; i < B; i += 256) acc += partial[i];

    #pragma unroll
    for (int off = 32; off > 0; off >>= 1)
        acc += __shfl_xor(acc, off, 64);

    __shared__ float ws[4];
    if ((tid & 63) == 0) ws[tid >> 6] = acc;
    __syncthreads();
    if (tid == 0) out[0] = -(ws[0] + ws[1] + ws[2] + ws[3]) / (float)(B * C);
}

extern "C" void kernel_launch(void* const* d_in, const int* in_sizes, int n_in,
                              void* d_out, int out_size, void* d_ws, size_t ws_size,
                              hipStream_t stream) {
    const int*   iword  = (const int*)d_in[0];
    const int*   owords = (const int*)d_in[1];
    const int*   nwords = (const int*)d_in[2];
    const float* emb1   = (const float*)d_in[3];
    const float* emb2   = (const float*)d_in[4];
    float* out     = (float*)d_out;
    float* partial = (float*)d_ws;  // B floats = 16 KB

    sgns_partial<<<B, 512, 0, stream>>>(iword, owords, nwords, emb1, emb2, partial);
    sgns_reduce<<<1, 256, 0, stream>>>(partial, out);
}